// Round 7
// baseline (4281.553 us; speedup 1.0000x reference)
//
#include <hip/hip_runtime.h>

// LSTM_38869454028951: B=512, T=365, F=16, H=256, 2 layers + linear head.
// Round 7: 2 independent WGs per CU. 32 bg x 16 ns = 512 WGs x 256 thr, M=16.
// bg cliques are independent -> co-resident WGs from different bgs overlap
// each other's sync-chain stalls and L2 weight streams. 4-wave map:
// (gate-pair gp) x (K-half kh); zb partials = 2. Weights streamed from L2.

#define T_STEPS 365
#define ASTR 552   // A row stride (ushorts)

typedef __attribute__((ext_vector_type(8))) short short8;
typedef __attribute__((ext_vector_type(8))) unsigned short ushort8;
typedef __attribute__((ext_vector_type(4))) float float4_;
typedef unsigned long long u64;
typedef unsigned int u32;

#define MFMA16(a, b, c) __builtin_amdgcn_mfma_f32_16x16x32_bf16((a), (b), (c), 0, 0, 0)
// zb layout: [gate 4][kh 2][col 16][row 17pad]
#define ZBI(G, KH, C, R) ((((G) * 2 + (KH)) * 16 + (C)) * 17 + (R))

__device__ __forceinline__ unsigned short f2bf(float v) {
    union { float f; u32 u; } a; a.f = v;
    u32 r = a.u + 0x7fffu + ((a.u >> 16) & 1u);  // RNE
    return (unsigned short)(r >> 16);
}
__device__ __forceinline__ float bf2f(unsigned short h) {
    union { u32 u; float f; } a; a.u = ((u32)h) << 16; return a.f;
}
__device__ __forceinline__ u32 packhl(float v) {
    unsigned short hi = f2bf(v);
    unsigned short lo = f2bf(v - bf2f(hi));
    return ((u32)hi << 16) | (u32)lo;
}
__device__ __forceinline__ float sigm(float x)  { return 1.f / (1.f + __expf(-x)); }
__device__ __forceinline__ float tanh_(float x) { return 2.f / (1.f + __expf(-2.f * x)) - 1.f; }

__device__ __forceinline__ void poll_ge(u32* c, u32 tgt) {
    while (__hip_atomic_load(c, __ATOMIC_RELAXED, __HIP_MEMORY_SCOPE_AGENT) < tgt)
        __builtin_amdgcn_s_sleep(1);
}

// ---------------- prep: blocked hi/lo weights + biases ----------------
// w1blk: [64 tiles][9 ks][16 rows][32 k]; ks<8: Whh1; ks==8: Wih1 (K pad 16->32)
// w2blk: [64][16][16][32]; ks<8: Wih2 (h1 input), ks>=8: Whh2 (h2 input)
__global__ void prep_w(
    const float* __restrict__ Wih1, const float* __restrict__ Whh1,
    const float* __restrict__ bih1, const float* __restrict__ bhh1,
    const float* __restrict__ Wih2, const float* __restrict__ Whh2,
    const float* __restrict__ bih2, const float* __restrict__ bhh2,
    unsigned short* __restrict__ w1h, unsigned short* __restrict__ w1l,
    unsigned short* __restrict__ w2h, unsigned short* __restrict__ w2l,
    float* __restrict__ bias1, float* __restrict__ bias2)
{
    const int tile = blockIdx.x;          // 64
    const int g = tile >> 4, ns = tile & 15;
    const int tid = threadIdx.x;          // 256

    for (int idx = tid; idx < 9 * 512; idx += 256) {
        int ks = idx >> 9, off = idx & 511, r = off >> 5, kk = off & 31;
        int R = g * 256 + ns * 16 + r;
        float v;
        if (ks < 8)       v = Whh1[R * 256 + ks * 32 + kk];
        else if (kk < 16) v = Wih1[R * 16 + kk];
        else              v = 0.f;
        unsigned short h = f2bf(v);
        size_t d = (size_t)(tile * 9 + ks) * 512 + off;
        w1h[d] = h; w1l[d] = f2bf(v - bf2f(h));
    }
    for (int idx = tid; idx < 16 * 512; idx += 256) {
        int ks = idx >> 9, off = idx & 511, r = off >> 5, kk = off & 31;
        int R = g * 256 + ns * 16 + r;
        int k = ks * 32 + kk;
        float v = (k < 256) ? Wih2[R * 256 + k] : Whh2[R * 256 + (k - 256)];
        unsigned short h = f2bf(v);
        size_t d = (size_t)(tile * 16 + ks) * 512 + off;
        w2h[d] = h; w2l[d] = f2bf(v - bf2f(h));
    }
    if (tid < 16) {
        int R = g * 256 + ns * 16 + tid;
        bias1[R] = bih1[R] + bhh1[R];
        bias2[R] = bih2[R] + bhh2[R];
    }
}

// stage 16 packed u32 (8 agent u64 loads) -> bf16 hi/lo LDS (shift unpack)
__device__ __forceinline__ void stage16p(const u32* src, unsigned short* dh, unsigned short* dl) {
    ushort8 H0, H1, L0, L1;
#pragma unroll
    for (int j = 0; j < 4; j++) {
        u64 v = __hip_atomic_load((const u64*)src + j, __ATOMIC_RELAXED, __HIP_MEMORY_SCOPE_AGENT);
        u32 a = (u32)v, b = (u32)(v >> 32);
        H0[2 * j] = (unsigned short)(a >> 16);     L0[2 * j] = (unsigned short)a;
        H0[2 * j + 1] = (unsigned short)(b >> 16); L0[2 * j + 1] = (unsigned short)b;
    }
#pragma unroll
    for (int j = 0; j < 4; j++) {
        u64 v = __hip_atomic_load((const u64*)src + 4 + j, __ATOMIC_RELAXED, __HIP_MEMORY_SCOPE_AGENT);
        u32 a = (u32)v, b = (u32)(v >> 32);
        H1[2 * j] = (unsigned short)(a >> 16);     L1[2 * j] = (unsigned short)a;
        H1[2 * j + 1] = (unsigned short)(b >> 16); L1[2 * j + 1] = (unsigned short)b;
    }
    *(ushort8*)(dh) = H0; *(ushort8*)(dh + 8) = H1;
    *(ushort8*)(dl) = L0; *(ushort8*)(dl + 8) = L1;
}

// ---------------- main ----------------
__global__ __launch_bounds__(256, 2) void lstm_main(
    const float* __restrict__ x,
    const unsigned short* __restrict__ w1h, const unsigned short* __restrict__ w1l,
    const unsigned short* __restrict__ w2h, const unsigned short* __restrict__ w2l,
    const float* __restrict__ bias1, const float* __restrict__ bias2,
    u32* hb1, u32* hb2, u32* prog,
    const float* __restrict__ Wlin, const float* __restrict__ blin,
    float* __restrict__ out)
{
    // A cols: [0..255]=h1_{t-1} (blocks 0-7), [256..287]=x_t (block 8),
    //         [288..543]=h2_{t-2} (blocks 9-16)
    __shared__ __align__(16) unsigned short A2h[16][ASTR];
    __shared__ __align__(16) unsigned short A2l[16][ASTR];
    __shared__ __align__(16) float zb1f[4 * 2 * 16 * 17];
    __shared__ __align__(16) float zb2f[4 * 2 * 16 * 17];
    __shared__ __align__(16) float hp[16][17];

    const int tid  = threadIdx.x;
    const int lane = tid & 63;
    const int wv   = tid >> 6;            // 4 waves
    const int quad = lane >> 4;
    const int r16  = lane & 15;
    const int gp   = wv & 1;              // gates {2gp, 2gp+1}
    const int kh   = wv >> 1;             // K-half
    const int bg   = blockIdx.x & 31;     // 32 batch groups of 16 rows
    const int ns   = blockIdx.x >> 5;     // 16 col slices
    const int loff = r16 * 32 + quad * 8;

    const int urow = tid >> 4;            // updater: batch row 0..15
    const int ucol = tid & 15;            // local col 0..15
    const int colg = ns * 16 + ucol;      // global hidden col

    u32* cnt = prog + bg * 32;            // one counter per bg, 128B apart

    float bi1[4], bi2[4];
#pragma unroll
    for (int gg = 0; gg < 4; gg++) {
        bi1[gg] = bias1[gg * 256 + colg];
        bi2[gg] = bias2[gg * 256 + colg];
    }

    // weight slice base pointers for this wave's two gates
    const unsigned short* w1ht[2]; const unsigned short* w1lt[2];
    const unsigned short* w2ht[2]; const unsigned short* w2lt[2];
#pragma unroll
    for (int gg = 0; gg < 2; gg++) {
        const int tl = (gp * 2 + gg) * 16 + ns;
        w1ht[gg] = w1h + (size_t)tl * 9 * 512;
        w1lt[gg] = w1l + (size_t)tl * 9 * 512;
        w2ht[gg] = w2h + (size_t)tl * 16 * 512;
        w2lt[gg] = w2l + (size_t)tl * 16 * 512;
    }

    // ---- zero A LDS; stage x_0 ----
    for (int i = tid; i < 16 * ASTR; i += 256) { (&A2h[0][0])[i] = 0; (&A2l[0][0])[i] = 0; }
    __syncthreads();
    {
        float v = x[((size_t)(bg * 16 + urow) * T_STEPS + 0) * 16 + ucol];
        unsigned short h = f2bf(v);
        A2h[urow][256 + ucol] = h;
        A2l[urow][256 + ucol] = f2bf(v - bf2f(h));
    }
    __syncthreads();

    float c1 = 0.f, c2 = 0.f;

#define TERM3S(Z, WHT, WLT, KS)                                               \
    {                                                                         \
        short8 bh = *(const short8*)((WHT) + (size_t)(KS) * 512 + loff);      \
        short8 bl = *(const short8*)((WLT) + (size_t)(KS) * 512 + loff);      \
        Z = MFMA16(ah, bh, Z); Z = MFMA16(al, bh, Z); Z = MFMA16(ah, bl, Z);  \
    }
#define LOADA(B)                                                              \
    short8 ah, al;                                                            \
    {                                                                         \
        const int co = (B) * 32 + quad * 8;                                   \
        ah = *(const short8*)&A2h[r16][co];                                   \
        al = *(const short8*)&A2l[r16][co];                                   \
    }

    for (int t = 0; t <= T_STEPS; t++) {   // 366 bodies
        const int p = t & 1;

        // ================= merged GEMM (z1: K=288, z2: K=512) =================
        float4_ z1a[2] = {{0.f,0.f,0.f,0.f},{0.f,0.f,0.f,0.f}};
        float4_ z2a[2] = {{0.f,0.f,0.f,0.f},{0.f,0.f,0.f,0.f}};

        if (kh == 0) {
#pragma unroll
            for (int j = 0; j < 5; j++) {     // h1 blocks 0-4
                LOADA(j)
#pragma unroll
                for (int gg = 0; gg < 2; gg++) {
                    TERM3S(z1a[gg], w1ht[gg], w1lt[gg], j)          // W1 ks j
                    if (j < 4) TERM3S(z2a[gg], w2ht[gg], w2lt[gg], j) // W2ih ks j
                }
            }
#pragma unroll
            for (int j = 0; j < 4; j++) {     // h2 blocks 9-12 -> W2hh ks 0-3
                LOADA(9 + j)
#pragma unroll
                for (int gg = 0; gg < 2; gg++)
                    TERM3S(z2a[gg], w2ht[gg], w2lt[gg], 8 + j)
            }
        } else {
            {   // h1 block 4 -> W2ih ks 4 only
                LOADA(4)
#pragma unroll
                for (int gg = 0; gg < 2; gg++)
                    TERM3S(z2a[gg], w2ht[gg], w2lt[gg], 4)
            }
#pragma unroll
            for (int j = 5; j < 8; j++) {     // h1 blocks 5-7
                LOADA(j)
#pragma unroll
                for (int gg = 0; gg < 2; gg++) {
                    TERM3S(z1a[gg], w1ht[gg], w1lt[gg], j)          // W1 ks j
                    TERM3S(z2a[gg], w2ht[gg], w2lt[gg], j)          // W2ih ks j
                }
            }
            {   // x block 8 -> W1 ks 8
                LOADA(8)
#pragma unroll
                for (int gg = 0; gg < 2; gg++)
                    TERM3S(z1a[gg], w1ht[gg], w1lt[gg], 8)
            }
#pragma unroll
            for (int j = 4; j < 8; j++) {     // h2 blocks 13-16 -> W2hh ks 4-7
                LOADA(9 + j)
#pragma unroll
                for (int gg = 0; gg < 2; gg++)
                    TERM3S(z2a[gg], w2ht[gg], w2lt[gg], 8 + j)
            }
        }

#pragma unroll
        for (int gg = 0; gg < 2; gg++) {
            const int gate = gp * 2 + gg;
            *(float4_*)&zb1f[ZBI(gate, kh, r16, quad * 4)] = z1a[gg];
            *(float4_*)&zb2f[ZBI(gate, kh, r16, quad * 4)] = z2a[gg];
        }
        __syncthreads();   // B1: zb ready; all A reads done

        // ---- reduce 2 kh partials; update h1_t and h2_{t-1}; publish ----
        {
            float zg1[4], zg2[4];
#pragma unroll
            for (int g4 = 0; g4 < 4; g4++) {
                zg1[g4] = bi1[g4] + zb1f[ZBI(g4, 0, ucol, urow)] + zb1f[ZBI(g4, 1, ucol, urow)];
                zg2[g4] = bi2[g4] + zb2f[ZBI(g4, 0, ucol, urow)] + zb2f[ZBI(g4, 1, ucol, urow)];
            }
            if (t <= T_STEPS - 1) {   // layer 1 -> h1_t
                c1 = sigm(zg1[1]) * c1 + sigm(zg1[0]) * tanh_(zg1[2]);
                float h1v = sigm(zg1[3]) * tanh_(c1);
                size_t o1 = (((size_t)p * 32 + bg) * 16 + urow) * 256 + colg;
                __hip_atomic_store(&hb1[o1], packhl(h1v), __ATOMIC_RELAXED, __HIP_MEMORY_SCOPE_AGENT);
            }
            {   // layer 2 -> h2_{t-1} (retimed)
                float nc2 = sigm(zg2[1]) * c2 + sigm(zg2[0]) * tanh_(zg2[2]);
                float h2v = sigm(zg2[3]) * tanh_(nc2);
                if (t == 0) { nc2 = 0.f; h2v = 0.f; }   // h2_{-1} = 0
                c2 = nc2;
                size_t o2 = (((size_t)(1 - p) * 32 + bg) * 16 + urow) * 256 + colg;
                __hip_atomic_store(&hb2[o2], packhl(h2v), __ATOMIC_RELAXED, __HIP_MEMORY_SCOPE_AGENT);
            }
        }
        __syncthreads();   // B2: publishes drained (vmcnt 0 at barrier)

        if (tid == 0)
            __hip_atomic_fetch_add(cnt, 1u, __ATOMIC_RELAXED, __HIP_MEMORY_SCOPE_AGENT);

        // ---- prefetch x_{t+1} into A block 8 (own LDS; GEMM reads done) ----
        {
            int tn = (t + 1 <= T_STEPS - 1) ? t + 1 : T_STEPS - 1;
            float v = x[((size_t)(bg * 16 + urow) * T_STEPS + tn) * 16 + ucol];
            unsigned short h = f2bf(v);
            A2h[urow][256 + ucol] = h;
            A2l[urow][256 + ucol] = f2bf(v - bf2f(h));
        }

        // ---- wait peers done body t; restage h1_t and h2_{t-1} ----
        poll_ge(cnt, (u32)(16 * (t + 1)));
        {
            const u32* s1 = hb1 + (((size_t)p * 32 + bg) * 16 + urow) * 256 + ucol * 16;
            const u32* s2 = hb2 + (((size_t)(1 - p) * 32 + bg) * 16 + urow) * 256 + ucol * 16;
            stage16p(s1, &A2h[urow][ucol * 16],       &A2l[urow][ucol * 16]);
            stage16p(s2, &A2h[urow][288 + ucol * 16], &A2l[urow][288 + ucol * 16]);
        }
        __syncthreads();   // B3: A ready for next body
    }

    // ---- head (ns==0): h2_364 is in LDS A (cols 288..543) after final restage
    if (ns != 0) return;
    {
        int row = tid >> 4, seg = tid & 15;
        float s = 0.f;
#pragma unroll
        for (int j = 0; j < 16; j++) {
            int k = seg * 16 + j;
            s += (bf2f(A2h[row][288 + k]) + bf2f(A2l[row][288 + k])) * Wlin[k];
        }
        hp[row][seg] = s;
    }
    __syncthreads();
    if (tid < 16) {
        float s = 0.f;
#pragma unroll
        for (int j = 0; j < 16; j++) s += hp[tid][j];
        out[bg * 16 + tid] = s + blin[0];
    }
}

extern "C" void kernel_launch(void* const* d_in, const int* in_sizes, int n_in,
                              void* d_out, int out_size, void* d_ws, size_t ws_size,
                              hipStream_t stream) {
    const float* x    = (const float*)d_in[0];
    const float* Wih1 = (const float*)d_in[1];
    const float* Whh1 = (const float*)d_in[2];
    const float* bih1 = (const float*)d_in[3];
    const float* bhh1 = (const float*)d_in[4];
    const float* Wih2 = (const float*)d_in[5];
    const float* Whh2 = (const float*)d_in[6];
    const float* bih2 = (const float*)d_in[7];
    const float* bhh2 = (const float*)d_in[8];
    const float* Wlin = (const float*)d_in[9];
    const float* blin = (const float*)d_in[10];
    float* out = (float*)d_out;

    char* pp = (char*)d_ws;
    unsigned short* w1h = (unsigned short*)pp; pp += (size_t)64 * 9 * 512 * 2;
    unsigned short* w1l = (unsigned short*)pp; pp += (size_t)64 * 9 * 512 * 2;
    unsigned short* w2h = (unsigned short*)pp; pp += (size_t)64 * 16 * 512 * 2;
    unsigned short* w2l = (unsigned short*)pp; pp += (size_t)64 * 16 * 512 * 2;
    float* bias1 = (float*)pp; pp += 1024 * 4;
    float* bias2 = (float*)pp; pp += 1024 * 4;
    char* zero_base = pp;
    u32* hb1 = (u32*)pp; pp += (size_t)2 * 32 * 16 * 256 * 4;   // 1 MB
    u32* hb2 = (u32*)pp; pp += (size_t)2 * 32 * 16 * 256 * 4;   // 1 MB
    u32* prog = (u32*)pp; pp += 32 * 32 * 4;                    // 1 counter/bg, 128B apart
    size_t zero_bytes = (size_t)(pp - zero_base);

    hipMemsetAsync(zero_base, 0, zero_bytes, stream);
    prep_w<<<64, 256, 0, stream>>>(Wih1, Whh1, bih1, bhh1, Wih2, Whh2, bih2, bhh2,
                                   w1h, w1l, w2h, w2l, bias1, bias2);
    lstm_main<<<512, 256, 0, stream>>>(x, w1h, w1l, w2h, w2l, bias1, bias2,
                                       hb1, hb2, prog, Wlin, blin, out);
}

// Round 8
// 2743.924 us; speedup vs baseline: 1.5604x; 1.5604x over previous
//
#include <hip/hip_runtime.h>

// LSTM_38869454028951: B=512, T=365, F=16, H=256, 2 layers + linear head.
// Round 8: r6 structure (16bg x 16ns, 512thr, gp x kq map, 3 barriers/body)
// + TRUE weight residency: all W fragments loaded ONCE pre-loop via inline-asm
// global_load_dwordx4 (non-rematerializable) under amdgpu_waves_per_eu(2,2)
// (256-VGPR budget, no occupancy incentive to spill). Per-body global traffic
// drops ~270KB -> ~70KB; the r7 A/B showed the weight stream cost ~4.2us/body.

#define T_STEPS 365
#define ASTR 552   // A row stride (ushorts)

typedef __attribute__((ext_vector_type(8))) short short8;
typedef __attribute__((ext_vector_type(8))) unsigned short ushort8;
typedef __attribute__((ext_vector_type(4))) float float4_;
typedef unsigned long long u64;
typedef unsigned int u32;

#define MFMA16(a, b, c) __builtin_amdgcn_mfma_f32_16x16x32_bf16((a), (b), (c), 0, 0, 0)
// zb layout: [gate 4][kq 4][col 16][row 36pad]
#define ZBI(G, Q, C, R) (((((G) * 4 + (Q)) * 16 + (C)) * 36) + (R))

__device__ __forceinline__ unsigned short f2bf(float v) {
    union { float f; u32 u; } a; a.f = v;
    u32 r = a.u + 0x7fffu + ((a.u >> 16) & 1u);  // RNE
    return (unsigned short)(r >> 16);
}
__device__ __forceinline__ float bf2f(unsigned short h) {
    union { u32 u; float f; } a; a.u = ((u32)h) << 16; return a.f;
}
__device__ __forceinline__ u32 packhl(float v) {
    unsigned short hi = f2bf(v);
    unsigned short lo = f2bf(v - bf2f(hi));
    return ((u32)hi << 16) | (u32)lo;
}
__device__ __forceinline__ float sigm(float x)  { return 1.f / (1.f + __expf(-x)); }
__device__ __forceinline__ float tanh_(float x) { return 2.f / (1.f + __expf(-2.f * x)) - 1.f; }

__device__ __forceinline__ void poll_ge(u32* c, u32 tgt) {
    while (__hip_atomic_load(c, __ATOMIC_RELAXED, __HIP_MEMORY_SCOPE_AGENT) < tgt)
        __builtin_amdgcn_s_sleep(1);
}

// asm 16B global load: output reg is asm-produced -> cannot be rematerialized.
__device__ __forceinline__ short8 gload16(const unsigned short* p) {
    short8 r;
    asm volatile("global_load_dwordx4 %0, %1, off" : "=v"(r) : "v"(p));
    return r;
}
__device__ __forceinline__ void vmwait0() { asm volatile("s_waitcnt vmcnt(0)" ::: "memory"); }
__device__ __forceinline__ void pinv(short8& r) { asm volatile("" : "+v"(r)); }

// ---------------- prep: blocked hi/lo weights + biases ----------------
// w1blk: [64 tiles][9 ks][16 rows][32 k]; ks<8: Whh1; ks==8: Wih1 (K pad 16->32)
// w2blk: [64][16][16][32]; ks<8: Wih2 (h1 input), ks>=8: Whh2 (h2 input)
__global__ void prep_w(
    const float* __restrict__ Wih1, const float* __restrict__ Whh1,
    const float* __restrict__ bih1, const float* __restrict__ bhh1,
    const float* __restrict__ Wih2, const float* __restrict__ Whh2,
    const float* __restrict__ bih2, const float* __restrict__ bhh2,
    unsigned short* __restrict__ w1h, unsigned short* __restrict__ w1l,
    unsigned short* __restrict__ w2h, unsigned short* __restrict__ w2l,
    float* __restrict__ bias1, float* __restrict__ bias2)
{
    const int tile = blockIdx.x;          // 64
    const int g = tile >> 4, ns = tile & 15;
    const int tid = threadIdx.x;          // 256

    for (int idx = tid; idx < 9 * 512; idx += 256) {
        int ks = idx >> 9, off = idx & 511, r = off >> 5, kk = off & 31;
        int R = g * 256 + ns * 16 + r;
        float v;
        if (ks < 8)       v = Whh1[R * 256 + ks * 32 + kk];
        else if (kk < 16) v = Wih1[R * 16 + kk];
        else              v = 0.f;
        unsigned short h = f2bf(v);
        size_t d = (size_t)(tile * 9 + ks) * 512 + off;
        w1h[d] = h; w1l[d] = f2bf(v - bf2f(h));
    }
    for (int idx = tid; idx < 16 * 512; idx += 256) {
        int ks = idx >> 9, off = idx & 511, r = off >> 5, kk = off & 31;
        int R = g * 256 + ns * 16 + r;
        int k = ks * 32 + kk;
        float v = (k < 256) ? Wih2[R * 256 + k] : Whh2[R * 256 + (k - 256)];
        unsigned short h = f2bf(v);
        size_t d = (size_t)(tile * 16 + ks) * 512 + off;
        w2h[d] = h; w2l[d] = f2bf(v - bf2f(h));
    }
    if (tid < 16) {
        int R = g * 256 + ns * 16 + tid;
        bias1[R] = bih1[R] + bhh1[R];
        bias2[R] = bih2[R] + bhh2[R];
    }
}

// stage 16 packed u32 (8 agent u64 loads) -> bf16 hi/lo LDS (shift unpack)
__device__ __forceinline__ void stage16p(const u32* src, unsigned short* dh, unsigned short* dl) {
    ushort8 H0, H1, L0, L1;
#pragma unroll
    for (int j = 0; j < 4; j++) {
        u64 v = __hip_atomic_load((const u64*)src + j, __ATOMIC_RELAXED, __HIP_MEMORY_SCOPE_AGENT);
        u32 a = (u32)v, b = (u32)(v >> 32);
        H0[2 * j] = (unsigned short)(a >> 16);     L0[2 * j] = (unsigned short)a;
        H0[2 * j + 1] = (unsigned short)(b >> 16); L0[2 * j + 1] = (unsigned short)b;
    }
#pragma unroll
    for (int j = 0; j < 4; j++) {
        u64 v = __hip_atomic_load((const u64*)src + 4 + j, __ATOMIC_RELAXED, __HIP_MEMORY_SCOPE_AGENT);
        u32 a = (u32)v, b = (u32)(v >> 32);
        H1[2 * j] = (unsigned short)(a >> 16);     L1[2 * j] = (unsigned short)a;
        H1[2 * j + 1] = (unsigned short)(b >> 16); L1[2 * j + 1] = (unsigned short)b;
    }
    *(ushort8*)(dh) = H0; *(ushort8*)(dh + 8) = H1;
    *(ushort8*)(dl) = L0; *(ushort8*)(dl + 8) = L1;
}

// ---------------- main ----------------
__global__ __attribute__((amdgpu_flat_work_group_size(512, 512), amdgpu_waves_per_eu(2, 2)))
void lstm_main(
    const float* __restrict__ x,
    const unsigned short* __restrict__ w1h, const unsigned short* __restrict__ w1l,
    const unsigned short* __restrict__ w2h, const unsigned short* __restrict__ w2l,
    const float* __restrict__ bias1, const float* __restrict__ bias2,
    u32* hb1, u32* hb2, u32* prog,
    const float* __restrict__ Wlin, const float* __restrict__ blin,
    float* __restrict__ out)
{
    // A cols: [0..255]=h1_{t-1}, [256..287]=x_t (272+ zero), [288..543]=h2_{t-2}
    __shared__ __align__(16) unsigned short A2h[32][ASTR];
    __shared__ __align__(16) unsigned short A2l[32][ASTR];
    __shared__ __align__(16) float zb1f[4 * 4 * 16 * 36];
    __shared__ __align__(16) float zb2f[4 * 4 * 16 * 36];
    __shared__ __align__(16) float hp[32][17];

    const int tid  = threadIdx.x;
    const int lane = tid & 63;
    const int wv   = tid >> 6;            // 8 waves
    const int quad = lane >> 4;
    const int r16  = lane & 15;
    const int kq   = wv & 3;              // K-quarter
    const int gp   = wv >> 2;             // gate pair: gates {2gp, 2gp+1}
    const int bg   = blockIdx.x & 15;     // batch group
    const int ns   = blockIdx.x >> 4;     // col slice
    const int loff = r16 * 32 + quad * 8;

    const int urow = tid >> 4;            // updater: batch row 0..31
    const int ucol = tid & 15;            // local col 0..15
    const int colg = ns * 16 + ucol;      // global hidden col

    u32* cnt = prog + bg * 32;

    float bi1[4], bi2[4];
#pragma unroll
    for (int gg = 0; gg < 4; gg++) {
        bi1[gg] = bias1[gg * 256 + colg];
        bi2[gg] = bias2[gg * 256 + colg];
    }

    // ---- preload ALL weights into registers, ONCE (asm loads, residency forced) ----
    short8 W1H[2][3], W1L[2][3], W2H[2][4], W2L[2][4];
#pragma unroll
    for (int gg = 0; gg < 2; gg++) {
        const int tl = (gp * 2 + gg) * 16 + ns;
        const unsigned short* b1h = w1h + (size_t)tl * 9 * 512;
        const unsigned short* b1l = w1l + (size_t)tl * 9 * 512;
        const unsigned short* b2h = w2h + (size_t)tl * 16 * 512;
        const unsigned short* b2l = w2l + (size_t)tl * 16 * 512;
#pragma unroll
        for (int j = 0; j < 2; j++) {
            const int ks = 2 * kq + j;
            W1H[gg][j] = gload16(b1h + (size_t)ks * 512 + loff);
            W1L[gg][j] = gload16(b1l + (size_t)ks * 512 + loff);
        }
        if (kq == 3) {   // x weights (Wih1, ks=8)
            W1H[gg][2] = gload16(b1h + (size_t)8 * 512 + loff);
            W1L[gg][2] = gload16(b1l + (size_t)8 * 512 + loff);
        }
#pragma unroll
        for (int j = 0; j < 2; j++) {
            const int ksA = 2 * kq + j;        // Wih2 (h1 input)
            const int ksB = 8 + 2 * kq + j;    // Whh2 (h2 input)
            W2H[gg][j]     = gload16(b2h + (size_t)ksA * 512 + loff);
            W2L[gg][j]     = gload16(b2l + (size_t)ksA * 512 + loff);
            W2H[gg][2 + j] = gload16(b2h + (size_t)ksB * 512 + loff);
            W2L[gg][2 + j] = gload16(b2l + (size_t)ksB * 512 + loff);
        }
    }
    vmwait0();
#pragma unroll
    for (int gg = 0; gg < 2; gg++) {
#pragma unroll
        for (int j = 0; j < 2; j++) { pinv(W1H[gg][j]); pinv(W1L[gg][j]); }
        if (kq == 3) { pinv(W1H[gg][2]); pinv(W1L[gg][2]); }
#pragma unroll
        for (int j = 0; j < 4; j++) { pinv(W2H[gg][j]); pinv(W2L[gg][j]); }
    }

    // ---- zero A LDS; stage x_0 ----
    for (int i = tid; i < 32 * ASTR; i += 512) { (&A2h[0][0])[i] = 0; (&A2l[0][0])[i] = 0; }
    __syncthreads();
    {
        float v = x[((size_t)(bg * 32 + urow) * T_STEPS + 0) * 16 + ucol];
        unsigned short h = f2bf(v);
        A2h[urow][256 + ucol] = h;
        A2l[urow][256 + ucol] = f2bf(v - bf2f(h));
    }
    __syncthreads();

    float c1 = 0.f, c2 = 0.f;

#define TERM3(A0, A1, WHR, WLR)                                \
    A0 = MFMA16(ah0, WHR, A0); A1 = MFMA16(ah1, WHR, A1);      \
    A0 = MFMA16(al0, WHR, A0); A1 = MFMA16(al1, WHR, A1);      \
    A0 = MFMA16(ah0, WLR, A0); A1 = MFMA16(ah1, WLR, A1);

    for (int t = 0; t <= T_STEPS; t++) {   // 366 bodies
        const int p = t & 1;

        // ================= merged GEMM (z1: K=288, z2: K=512) =================
        float4_ z1a[2][2] = {{{0.f,0.f,0.f,0.f},{0.f,0.f,0.f,0.f}},
                             {{0.f,0.f,0.f,0.f},{0.f,0.f,0.f,0.f}}};
        float4_ z2a[2][2] = {{{0.f,0.f,0.f,0.f},{0.f,0.f,0.f,0.f}},
                             {{0.f,0.f,0.f,0.f},{0.f,0.f,0.f,0.f}}};

#pragma unroll
        for (int j = 0; j < 2; j++) {      // h1 blocks: feed BOTH z1 and z2
            const int co = (2 * kq + j) * 32 + quad * 8;
            short8 ah0 = *(const short8*)&A2h[r16][co];
            short8 al0 = *(const short8*)&A2l[r16][co];
            short8 ah1 = *(const short8*)&A2h[r16 + 16][co];
            short8 al1 = *(const short8*)&A2l[r16 + 16][co];
#pragma unroll
            for (int gg = 0; gg < 2; gg++) {
                TERM3(z1a[gg][0], z1a[gg][1], W1H[gg][j], W1L[gg][j])
                TERM3(z2a[gg][0], z2a[gg][1], W2H[gg][j], W2L[gg][j])
            }
        }
        if (kq == 3) {                     // x block -> z1
            const int co = 256 + quad * 8;
            short8 ah0 = *(const short8*)&A2h[r16][co];
            short8 al0 = *(const short8*)&A2l[r16][co];
            short8 ah1 = *(const short8*)&A2h[r16 + 16][co];
            short8 al1 = *(const short8*)&A2l[r16 + 16][co];
#pragma unroll
            for (int gg = 0; gg < 2; gg++) {
                TERM3(z1a[gg][0], z1a[gg][1], W1H[gg][2], W1L[gg][2])
            }
        }
#pragma unroll
        for (int j = 0; j < 2; j++) {      // h2 blocks -> z2
            const int co = 288 + (2 * kq + j) * 32 + quad * 8;
            short8 ah0 = *(const short8*)&A2h[r16][co];
            short8 al0 = *(const short8*)&A2l[r16][co];
            short8 ah1 = *(const short8*)&A2h[r16 + 16][co];
            short8 al1 = *(const short8*)&A2l[r16 + 16][co];
#pragma unroll
            for (int gg = 0; gg < 2; gg++) {
                TERM3(z2a[gg][0], z2a[gg][1], W2H[gg][2 + j], W2L[gg][2 + j])
            }
        }

#pragma unroll
        for (int gg = 0; gg < 2; gg++) {
            const int gate = gp * 2 + gg;
            *(float4_*)&zb1f[ZBI(gate, kq, r16, quad * 4)]      = z1a[gg][0];
            *(float4_*)&zb1f[ZBI(gate, kq, r16, 16 + quad * 4)] = z1a[gg][1];
            *(float4_*)&zb2f[ZBI(gate, kq, r16, quad * 4)]      = z2a[gg][0];
            *(float4_*)&zb2f[ZBI(gate, kq, r16, 16 + quad * 4)] = z2a[gg][1];
        }
        __syncthreads();   // B1: zb ready; all A reads done

        // ---- reduce 4 kq partials; update h1_t and h2_{t-1}; publish ----
        {
            float zg1[4], zg2[4];
#pragma unroll
            for (int g4 = 0; g4 < 4; g4++) {
                float s1 = bi1[g4], s2 = bi2[g4];
#pragma unroll
                for (int q = 0; q < 4; q++) {
                    s1 += zb1f[ZBI(g4, q, ucol, urow)];
                    s2 += zb2f[ZBI(g4, q, ucol, urow)];
                }
                zg1[g4] = s1; zg2[g4] = s2;
            }
            // layer 1 -> h1_t
            c1 = sigm(zg1[1]) * c1 + sigm(zg1[0]) * tanh_(zg1[2]);
            float h1v = sigm(zg1[3]) * tanh_(c1);
            size_t o1 = (((size_t)p * 16 + bg) * 32 + urow) * 256 + colg;
            __hip_atomic_store(&hb1[o1], packhl(h1v), __ATOMIC_RELAXED, __HIP_MEMORY_SCOPE_AGENT);
            // layer 2 -> h2_{t-1} (retimed)
            float nc2 = sigm(zg2[1]) * c2 + sigm(zg2[0]) * tanh_(zg2[2]);
            float h2v = sigm(zg2[3]) * tanh_(nc2);
            if (t == 0) { nc2 = 0.f; h2v = 0.f; }   // h2_{-1} = 0
            c2 = nc2;
            size_t o2 = (((size_t)(1 - p) * 16 + bg) * 32 + urow) * 256 + colg;
            __hip_atomic_store(&hb2[o2], packhl(h2v), __ATOMIC_RELAXED, __HIP_MEMORY_SCOPE_AGENT);
        }
        __syncthreads();   // B2: publishes drained (vmcnt 0 at barrier)

        if (tid == 0)
            __hip_atomic_fetch_add(cnt, 1u, __ATOMIC_RELAXED, __HIP_MEMORY_SCOPE_AGENT);

        // ---- prefetch x_{t+1} into A block 8 (own LDS; GEMM reads done) ----
        {
            int tn = (t + 1 <= T_STEPS - 1) ? t + 1 : T_STEPS - 1;
            float v = x[((size_t)(bg * 32 + urow) * T_STEPS + tn) * 16 + ucol];
            unsigned short h = f2bf(v);
            A2h[urow][256 + ucol] = h;
            A2l[urow][256 + ucol] = f2bf(v - bf2f(h));
        }

        // ---- wait peers done body t; restage h1_t and h2_{t-1} ----
        poll_ge(cnt, (u32)(16 * (t + 1)));
        {
            const u32* s1 = hb1 + (((size_t)p * 16 + bg) * 32 + urow) * 256 + ucol * 16;
            const u32* s2 = hb2 + (((size_t)(1 - p) * 16 + bg) * 32 + urow) * 256 + ucol * 16;
            stage16p(s1, &A2h[urow][ucol * 16],       &A2l[urow][ucol * 16]);
            stage16p(s2, &A2h[urow][288 + ucol * 16], &A2l[urow][288 + ucol * 16]);
        }
        __syncthreads();   // B3: A ready for next body
    }

    // ---- head (ns==0): out[b] = h2_364 . Wlin + blin ; h2_364 in slot 0 ----
    if (ns != 0) return;
    {
        int row = tid >> 4, seg = tid & 15;
        const u32* src = hb2 + ((size_t)bg * 32 + row) * 256 + seg * 16;   // slot 0
        float s = 0.f;
#pragma unroll
        for (int j = 0; j < 16; j++) {
            u32 v = __hip_atomic_load(&src[j], __ATOMIC_RELAXED, __HIP_MEMORY_SCOPE_AGENT);
            s += (bf2f((unsigned short)(v >> 16)) + bf2f((unsigned short)v)) * Wlin[seg * 16 + j];
        }
        hp[row][seg] = s;
    }
    __syncthreads();
    if (tid < 32) {
        float s = 0.f;
#pragma unroll
        for (int j = 0; j < 16; j++) s += hp[tid][j];
        out[bg * 32 + tid] = s + blin[0];
    }
}

extern "C" void kernel_launch(void* const* d_in, const int* in_sizes, int n_in,
                              void* d_out, int out_size, void* d_ws, size_t ws_size,
                              hipStream_t stream) {
    const float* x    = (const float*)d_in[0];
    const float* Wih1 = (const float*)d_in[1];
    const float* Whh1 = (const float*)d_in[2];
    const float* bih1 = (const float*)d_in[3];
    const float* bhh1 = (const float*)d_in[4];
    const float* Wih2 = (const float*)d_in[5];
    const float* Whh2 = (const float*)d_in[6];
    const float* bih2 = (const float*)d_in[7];
    const float* bhh2 = (const float*)d_in[8];
    const float* Wlin = (const float*)d_in[9];
    const float* blin = (const float*)d_in[10];
    float* out = (float*)d_out;

    char* pp = (char*)d_ws;
    unsigned short* w1h = (unsigned short*)pp; pp += (size_t)64 * 9 * 512 * 2;
    unsigned short* w1l = (unsigned short*)pp; pp += (size_t)64 * 9 * 512 * 2;
    unsigned short* w2h = (unsigned short*)pp; pp += (size_t)64 * 16 * 512 * 2;
    unsigned short* w2l = (unsigned short*)pp; pp += (size_t)64 * 16 * 512 * 2;
    float* bias1 = (float*)pp; pp += 1024 * 4;
    float* bias2 = (float*)pp; pp += 1024 * 4;
    char* zero_base = pp;
    u32* hb1 = (u32*)pp; pp += (size_t)2 * 16 * 32 * 256 * 4;   // 1 MB
    u32* hb2 = (u32*)pp; pp += (size_t)2 * 16 * 32 * 256 * 4;   // 1 MB
    u32* prog = (u32*)pp; pp += 16 * 32 * 4;                    // 1 counter/bg, 128B apart
    size_t zero_bytes = (size_t)(pp - zero_base);

    hipMemsetAsync(zero_base, 0, zero_bytes, stream);
    prep_w<<<64, 256, 0, stream>>>(Wih1, Whh1, bih1, bhh1, Wih2, Whh2, bih2, bhh2,
                                   w1h, w1l, w2h, w2l, bias1, bias2);
    lstm_main<<<256, 512, 0, stream>>>(x, w1h, w1l, w2h, w2l, bias1, bias2,
                                       hb1, hb2, prog, Wlin, blin, out);
}